// Round 1
// 1216.425 us; speedup vs baseline: 2.3506x; 2.3506x over previous
//
#include <hip/hip_runtime.h>

#define TOK   8192      // B*S tokens
#define DDIM  1024
#define FDIM  4096
#define NEXP  8

typedef __attribute__((ext_vector_type(8))) short short8;
typedef __attribute__((ext_vector_type(4))) float float4_t;

// ---------- helpers ----------
__device__ __forceinline__ unsigned short f2b(float f) {
    union { float f; unsigned int i; } v; v.f = f;
    unsigned int r = v.i + 0x7FFFu + ((v.i >> 16) & 1u);   // RNE
    return (unsigned short)(r >> 16);
}

// async global->LDS, 16B per lane. LDS base must be wave-uniform; HW writes
// lane's 16B at lds_base + lane*16. Global address is per-lane (gather OK).
__device__ __forceinline__ void g2lds16(const unsigned short* g, unsigned short* l) {
    __builtin_amdgcn_global_load_lds(
        (const __attribute__((address_space(1))) unsigned int*)g,
        (__attribute__((address_space(3))) unsigned int*)l, 16, 0, 0);
}

// ---------- X fp32 -> bf16 ----------
__global__ __launch_bounds__(256) void prep_x(
    const float* __restrict__ X, unsigned short* __restrict__ Xb)
{
    int i = blockIdx.x * 256 + threadIdx.x;   // indexes groups of 4
    float4 v = reinterpret_cast<const float4*>(X)[i];
    union { unsigned short u[4]; uint2 p; } o;
    o.u[0] = f2b(v.x); o.u[1] = f2b(v.y); o.u[2] = f2b(v.z); o.u[3] = f2b(v.w);
    reinterpret_cast<uint2*>(Xb)[i] = o.p;
}

// ---------- zero expert counters ----------
__global__ void zero_counts(int* __restrict__ counts) {
    if (threadIdx.x < NEXP) counts[threadIdx.x] = 0;
}

// ---------- router: fp32 logits, top-2, softmax (fp32 weights), scatter ----------
__global__ __launch_bounds__(256) void router_kernel(
    const float* __restrict__ X, const float* __restrict__ GW,
    int* __restrict__ counts, int* __restrict__ plist, float* __restrict__ wlist)
{
    int lane = threadIdx.x & 63;
    int wv   = threadIdx.x >> 6;
    int t    = blockIdx.x * 4 + wv;

    float acc[NEXP];
#pragma unroll
    for (int e = 0; e < NEXP; ++e) acc[e] = 0.f;

#pragma unroll
    for (int i = 0; i < 16; ++i) {
        int d = lane + 64 * i;
        float x = X[(size_t)t * DDIM + d];
        float4 g0 = reinterpret_cast<const float4*>(&GW[d * NEXP])[0];
        float4 g1 = reinterpret_cast<const float4*>(&GW[d * NEXP])[1];
        acc[0] += x * g0.x; acc[1] += x * g0.y; acc[2] += x * g0.z; acc[3] += x * g0.w;
        acc[4] += x * g1.x; acc[5] += x * g1.y; acc[6] += x * g1.z; acc[7] += x * g1.w;
    }
#pragma unroll
    for (int off = 32; off > 0; off >>= 1) {
#pragma unroll
        for (int e = 0; e < NEXP; ++e)
            acc[e] += __shfl_xor(acc[e], off, 64);
    }
    if (lane == 0) {
        int be = 0; float b0v = acc[0];
#pragma unroll
        for (int e = 1; e < NEXP; ++e) if (acc[e] > b0v) { b0v = acc[e]; be = e; }
        int se = -1; float b1v = -INFINITY;
#pragma unroll
        for (int e = 0; e < NEXP; ++e) if (e != be && acc[e] > b1v) { b1v = acc[e]; se = e; }
        if (se < 0 || se > 7) se = (be + 1) & 7;   // defensive (NaN logits)
        float e1 = expf(b1v - b0v);                // <= 1 for real inputs
        float w0 = 1.f / (1.f + e1);
        float w1 = e1 / (1.f + e1);
        int p0 = atomicAdd(&counts[be], 1);
        if (p0 >= 0 && p0 < TOK) { plist[be * TOK + p0] = 2 * t;     wlist[be * TOK + p0] = w0; }
        int p1 = atomicAdd(&counts[se], 1);
        if (p1 >= 0 && p1 < TOK) { plist[se * TOK + p1] = 2 * t + 1; wlist[se * TOK + p1] = w1; }
    }
}

// ---------- transpose wi0/wi1 fp32 [d][f] -> W01t bf16 [E][2F][D], 16-row interleave ----------
__global__ __launch_bounds__(256) void transpose_w01(
    const float* __restrict__ wi0, const float* __restrict__ wi1,
    unsigned short* __restrict__ w01t)
{
    __shared__ float sh[32][33];
    int z = blockIdx.z; int e = z >> 1; int which = z & 1;
    const float* src = (which ? wi1 : wi0) + (size_t)e * DDIM * FDIM; // [1024][4096]
    unsigned short* dst = w01t + (size_t)e * 2 * FDIM * DDIM;
    int tx = threadIdx.x, ty = threadIdx.y;
    int r0 = blockIdx.y * 32;   // d
    int c0 = blockIdx.x * 32;   // f
#pragma unroll
    for (int i = 0; i < 4; ++i)
        sh[ty + 8 * i][tx] = src[(size_t)(r0 + ty + 8 * i) * FDIM + c0 + tx];
    __syncthreads();
#pragma unroll
    for (int i = 0; i < 4; ++i) {
        int f  = c0 + ty + 8 * i;
        int rp = 32 * (f >> 4) + 16 * which + (f & 15);
        dst[(size_t)rp * DDIM + r0 + tx] = f2b(sh[tx][ty + 8 * i]);
    }
}

// ---------- transpose wo fp32 [f][d] -> WOt bf16 [E][D][F] ----------
__global__ __launch_bounds__(256) void transpose_plain(
    const float* __restrict__ wo, unsigned short* __restrict__ wot)
{
    __shared__ float sh[32][33];
    int e = blockIdx.z;
    const float* src = wo + (size_t)e * FDIM * DDIM;     // [4096][1024]
    unsigned short* dst = wot + (size_t)e * DDIM * FDIM; // [1024][4096]
    int tx = threadIdx.x, ty = threadIdx.y;
    int r0 = blockIdx.y * 32;   // f
    int c0 = blockIdx.x * 32;   // d
#pragma unroll
    for (int i = 0; i < 4; ++i)
        sh[ty + 8 * i][tx] = src[(size_t)(r0 + ty + 8 * i) * DDIM + c0 + tx];
    __syncthreads();
#pragma unroll
    for (int i = 0; i < 4; ++i)
        dst[(size_t)(c0 + ty + 8 * i) * FDIM + r0 + tx] = f2b(sh[tx][ty + 8 * i]);
}

// ---------- GEMM1: H[pair][f] = silu(x@wi0) * (x@wi1), gathered bf16 rows ----------
// 128 pair-rows x 128 W01t-rows (= 64 f, both matrices), BK=64, 16x16x32 MFMA.
// LDS layout: linear [row][8 chunks of 16B] but DATA is XOR-swizzled: chunk c of
// row r lives at slot (c ^ (r&7)). Achieved with linear global_load_lds dest +
// pre-swizzled global source column; reads apply the same XOR. (T2 / G4, rule 21)
__global__ __launch_bounds__(256) void gemm1_kernel(
    const unsigned short* __restrict__ Xb,    // [TOK][D] bf16
    const unsigned short* __restrict__ W01t,  // [E][2F][D] bf16
    const int* __restrict__ counts, const int* __restrict__ plist,
    unsigned short* __restrict__ H)           // [2*TOK][F] bf16
{
    int e   = blockIdx.z;
    int cnt = counts[e];
    cnt = cnt < 0 ? 0 : (cnt > TOK ? TOK : cnt);
    int m0  = blockIdx.y * 128;
    if (m0 >= cnt) return;
    int valid = cnt - m0; if (valid > 128) valid = 128;
    int bx = blockIdx.x;                      // 0..63 over 2F/128

    __shared__ __align__(16) unsigned short sA[128 * 64];
    __shared__ __align__(16) unsigned short sB[128 * 64];
    __shared__ int sPair[128];

    int tid = threadIdx.x, lane = tid & 63, wv = tid >> 6;
    if (tid < 128) {
        int idx = (tid < valid) ? (m0 + tid) : m0;   // clamp padding rows
        sPair[tid] = plist[e * TOK + idx] & (2 * TOK - 1);
    }
    __syncthreads();

    const unsigned short* gA[4]; unsigned short* lA[4];
    const unsigned short* gB[4]; unsigned short* lB[4];
    const unsigned short* Wb = W01t + (size_t)e * (2 * FDIM) * DDIM;
#pragma unroll
    for (int i = 0; i < 4; ++i) {
        int j  = 4 * wv + i;                // staging slot 0..15, 8 rows each
        int r8 = lane >> 3;
        int r  = 8 * j + r8;                // LDS row
        int c  = (lane & 7) ^ r8;           // pre-swizzled source chunk
        gA[i] = Xb + (size_t)(sPair[r] >> 1) * DDIM + c * 8;
        gB[i] = Wb + (size_t)(bx * 128 + r) * DDIM + c * 8;
        lA[i] = &sA[j * 512];               // wave-uniform LDS base
        lB[i] = &sB[j * 512];
    }

    float4_t C[4][4];
#pragma unroll
    for (int a = 0; a < 4; ++a)
#pragma unroll
        for (int b = 0; b < 4; ++b) C[a][b] = (float4_t)0.f;

    int mrow = (wv >> 1) * 64;   // wave's 4 m-tiles
    int ncol = (wv & 1) * 64;    // wave's 4 n-tiles
    int rr = lane & 15, quad = lane >> 4;

    // prologue: issue tile 0
#pragma unroll
    for (int i = 0; i < 4; ++i) { g2lds16(gA[i], lA[i]); gA[i] += 64; }
#pragma unroll
    for (int i = 0; i < 4; ++i) { g2lds16(gB[i], lB[i]); gB[i] += 64; }

    for (int kk = 0; kk < DDIM / 64; ++kk) {
        __syncthreads();   // loads landed (vmcnt drained at barrier)
#pragma unroll
        for (int ks = 0; ks < 2; ++ks) {
            short8 a[4], b[4];
#pragma unroll
            for (int mt = 0; mt < 4; ++mt)
                a[mt] = *(const short8*)&sA[(mrow + mt * 16 + rr) * 64 +
                                            (((ks * 4 + quad) ^ (rr & 7)) * 8)];
#pragma unroll
            for (int nt = 0; nt < 4; ++nt)
                b[nt] = *(const short8*)&sB[(ncol + nt * 16 + rr) * 64 +
                                            (((ks * 4 + quad) ^ (rr & 7)) * 8)];
#pragma unroll
            for (int mt = 0; mt < 4; ++mt)
#pragma unroll
                for (int nt = 0; nt < 4; ++nt)
                    C[mt][nt] = __builtin_amdgcn_mfma_f32_16x16x32_bf16(a[mt], b[nt], C[mt][nt], 0, 0, 0);
        }
        __syncthreads();   // all LDS reads of this tile done
        if (kk + 1 < DDIM / 64) {
#pragma unroll
            for (int i = 0; i < 4; ++i) { g2lds16(gA[i], lA[i]); gA[i] += 64; }
#pragma unroll
            for (int i = 0; i < 4; ++i) { g2lds16(gB[i], lB[i]); gB[i] += 64; }
        }
    }

    // epilogue: silu(a0)*a1, repack through LDS (reuse sA) so H stores are
    // full 128B contiguous row segments instead of scattered 32B partials.
    {
        unsigned short* sH = sA;   // [128 rows][64 f], quad-XOR-swizzled 32B chunks
#pragma unroll
        for (int mt = 0; mt < 4; ++mt) {
#pragma unroll
            for (int i = 0; i < 4; ++i) {
                int row = mrow + mt * 16 + quad * 4 + i;   // (row>>2)&3 == quad
#pragma unroll
                for (int ntp = 0; ntp < 2; ++ntp) {
                    float a0 = C[mt][2 * ntp][i];      // wi0 (even 16-group)
                    float a1 = C[mt][2 * ntp + 1][i];  // wi1 (odd 16-group)
                    float h  = (a0 / (1.f + expf(-a0))) * a1;
                    int fl = ((wv & 1) * 2 + ntp) * 16 + rr;
                    sH[row * 64 + (fl ^ (quad << 4))] = f2b(h);
                }
            }
        }
        __syncthreads();
        int r0 = tid >> 3;            // 0..31
        int fo = (tid & 7) * 8;       // 16B chunk within row
#pragma unroll
        for (int p = 0; p < 4; ++p) {
            int row = p * 32 + r0;
            if (row < valid) {
                int swz = ((row >> 2) & 3) << 4;
                uint4 v = *(const uint4*)&sH[row * 64 + (fo ^ swz)];
                *(uint4*)(H + (size_t)sPair[row] * FDIM + bx * 64 + fo) = v;
            }
        }
    }
}

// ---------- GEMM2: Y[pair][d] = w * (H[pair] @ wo[e])  (fp32 out) ----------
__global__ __launch_bounds__(256) void gemm2_kernel(
    const unsigned short* __restrict__ H,     // [2*TOK][F] bf16
    const unsigned short* __restrict__ Wot,   // [E][D][F] bf16
    const int* __restrict__ counts, const int* __restrict__ plist,
    const float* __restrict__ wlist, float* __restrict__ Y)  // [2*TOK][D] fp32
{
    int e   = blockIdx.z;
    int cnt = counts[e];
    cnt = cnt < 0 ? 0 : (cnt > TOK ? TOK : cnt);
    int m0  = blockIdx.y * 128;
    if (m0 >= cnt) return;
    int valid = cnt - m0; if (valid > 128) valid = 128;
    int bx = blockIdx.x;                      // 0..7 over D/128

    __shared__ __align__(16) unsigned short sA[128 * 64];
    __shared__ __align__(16) unsigned short sB[128 * 64];
    __shared__ int   sPair[128];
    __shared__ float sWgt[128];

    int tid = threadIdx.x, lane = tid & 63, wv = tid >> 6;
    if (tid < 128) {
        int idx = (tid < valid) ? (m0 + tid) : m0;
        sPair[tid] = plist[e * TOK + idx] & (2 * TOK - 1);
        sWgt[tid]  = wlist[e * TOK + idx];
    }
    __syncthreads();

    const unsigned short* gA[4]; unsigned short* lA[4];
    const unsigned short* gB[4]; unsigned short* lB[4];
    const unsigned short* Wb = Wot + (size_t)e * DDIM * FDIM;
#pragma unroll
    for (int i = 0; i < 4; ++i) {
        int j  = 4 * wv + i;
        int r8 = lane >> 3;
        int r  = 8 * j + r8;
        int c  = (lane & 7) ^ r8;
        gA[i] = H + (size_t)sPair[r] * FDIM + c * 8;
        gB[i] = Wb + (size_t)(bx * 128 + r) * FDIM + c * 8;
        lA[i] = &sA[j * 512];
        lB[i] = &sB[j * 512];
    }

    float4_t C[4][4];
#pragma unroll
    for (int a = 0; a < 4; ++a)
#pragma unroll
        for (int b = 0; b < 4; ++b) C[a][b] = (float4_t)0.f;

    int mrow = (wv >> 1) * 64;
    int ncol = (wv & 1) * 64;
    int rr = lane & 15, quad = lane >> 4;

#pragma unroll
    for (int i = 0; i < 4; ++i) { g2lds16(gA[i], lA[i]); gA[i] += 64; }
#pragma unroll
    for (int i = 0; i < 4; ++i) { g2lds16(gB[i], lB[i]); gB[i] += 64; }

    for (int kk = 0; kk < FDIM / 64; ++kk) {
        __syncthreads();
#pragma unroll
        for (int ks = 0; ks < 2; ++ks) {
            short8 a[4], b[4];
#pragma unroll
            for (int mt = 0; mt < 4; ++mt)
                a[mt] = *(const short8*)&sA[(mrow + mt * 16 + rr) * 64 +
                                            (((ks * 4 + quad) ^ (rr & 7)) * 8)];
#pragma unroll
            for (int nt = 0; nt < 4; ++nt)
                b[nt] = *(const short8*)&sB[(ncol + nt * 16 + rr) * 64 +
                                            (((ks * 4 + quad) ^ (rr & 7)) * 8)];
#pragma unroll
            for (int mt = 0; mt < 4; ++mt)
#pragma unroll
                for (int nt = 0; nt < 4; ++nt)
                    C[mt][nt] = __builtin_amdgcn_mfma_f32_16x16x32_bf16(a[mt], b[nt], C[mt][nt], 0, 0, 0);
        }
        __syncthreads();
        if (kk + 1 < FDIM / 64) {
#pragma unroll
            for (int i = 0; i < 4; ++i) { g2lds16(gA[i], lA[i]); gA[i] += 64; }
#pragma unroll
            for (int i = 0; i < 4; ++i) { g2lds16(gB[i], lB[i]); gB[i] += 64; }
        }
    }

    // epilogue: 16 lanes x 4B = 64B contiguous aligned segments — already coalesced
#pragma unroll
    for (int mt = 0; mt < 4; ++mt) {
#pragma unroll
        for (int i = 0; i < 4; ++i) {
            int row = mrow + mt * 16 + quad * 4 + i;
            if (row >= valid) continue;
            float w = sWgt[row];
            float* dst = Y + (size_t)sPair[row] * DDIM + bx * 128;
#pragma unroll
            for (int nt = 0; nt < 4; ++nt)
                dst[ncol + nt * 16 + rr] = w * C[mt][nt][i];
        }
    }
}

// ---------- combine: out[t] = Y[2t] + Y[2t+1] (fp32) ----------
__global__ __launch_bounds__(256) void combine_kernel(
    const float* __restrict__ Y, float* __restrict__ out)
{
    int t  = blockIdx.x;
    int d0 = threadIdx.x * 4;
    float4 a = *(const float4*)(Y + (size_t)(2 * t) * DDIM + d0);
    float4 b = *(const float4*)(Y + (size_t)(2 * t + 1) * DDIM + d0);
    float4 o; o.x = a.x + b.x; o.y = a.y + b.y; o.z = a.z + b.z; o.w = a.w + b.w;
    *(float4*)(out + (size_t)t * DDIM + d0) = o;
}

// ---------- launch ----------
extern "C" void kernel_launch(void* const* d_in, const int* in_sizes, int n_in,
                              void* d_out, int out_size, void* d_ws, size_t ws_size,
                              hipStream_t stream)
{
    const float* X   = (const float*)d_in[0];
    const float* GW  = (const float*)d_in[1];
    const float* WI0 = (const float*)d_in[2];
    const float* WI1 = (const float*)d_in[3];
    const float* WO  = (const float*)d_in[4];
    float* OUT = (float*)d_out;

    // ws layout (bytes). Y (fp32, 67108864 B) aliases W01t's region (dead after gemm1).
    const size_t OFF_W01T = 0;            // 134217728 B (bf16)
    const size_t OFF_WOT  = 134217728;    // 67108864 B (bf16)
    const size_t OFF_H    = 201326592;    // 134217728 B (bf16)
    const size_t OFF_XB   = 335544320;    // 16777216 B (bf16)
    const size_t OFF_CNT  = 352321536;    // 1024 B
    const size_t OFF_PL   = 352322560;    // 262144 B
    const size_t OFF_WL   = 352584704;    // 262144 B
    const size_t WS_NEED  = 352846848;
    if (ws_size < WS_NEED) return;        // diagnostic: clean absmax=1.21 fail => ws too small

    char* ws = (char*)d_ws;
    unsigned short* W01t  = (unsigned short*)(ws + OFF_W01T);
    float*          Y     = (float*)(ws + OFF_W01T);          // alias, used after gemm1
    unsigned short* WOt   = (unsigned short*)(ws + OFF_WOT);
    unsigned short* H     = (unsigned short*)(ws + OFF_H);
    unsigned short* Xb    = (unsigned short*)(ws + OFF_XB);
    int*            cnts  = (int*)(ws + OFF_CNT);
    int*            plist = (int*)(ws + OFF_PL);
    float*          wlist = (float*)(ws + OFF_WL);

    zero_counts<<<1, 64, 0, stream>>>(cnts);
    prep_x<<<(TOK * DDIM / 4) / 256, 256, 0, stream>>>(X, Xb);
    transpose_w01<<<dim3(FDIM / 32, DDIM / 32, 2 * NEXP), dim3(32, 8, 1), 0, stream>>>(WI0, WI1, W01t);
    transpose_plain<<<dim3(DDIM / 32, FDIM / 32, NEXP), dim3(32, 8, 1), 0, stream>>>(WO, WOt);
    router_kernel<<<TOK / 4, 256, 0, stream>>>(X, GW, cnts, plist, wlist);
    gemm1_kernel<<<dim3(2 * FDIM / 128, TOK / 128, NEXP), dim3(256), 0, stream>>>(Xb, W01t, cnts, plist, H);
    gemm2_kernel<<<dim3(DDIM / 128, TOK / 128, NEXP), dim3(256), 0, stream>>>(H, WOt, cnts, plist, wlist, Y);
    combine_kernel<<<TOK, 256, 0, stream>>>(Y, OUT);
}